// Round 9
// baseline (32211.453 us; speedup 1.0000x reference)
//
#include <hip/hip_runtime.h>
#include <math.h>

typedef unsigned short u16;
typedef __attribute__((ext_vector_type(8))) short bf16x8;
typedef __attribute__((ext_vector_type(4))) float f32x4;

#define MFMA(a, b, c) __builtin_amdgcn_mfma_f32_16x16x32_bf16(a, b, c, 0, 0, 0)

#define Bsz 512
#define Tsz 128
#define Dsz 256
#define CSs 10
#define Hsz 384
#define Gsz 1542
#define HSz 64
#define Gp  1568
#define NGT 98       // Gp/16
#define KTH 12       // 384/32
#define KTX 8        // 256/32
#define KTC 120      // 3840/32
#define NRG 32       // row-groups = blocks, 16 rows each
#define XOP 1576     // s_xo row stride (floats)

// ---------------- ws layout (byte offsets) ----------------
constexpr size_t O_WPK  = 0;                                   // u16 98*12*2*512
constexpr size_t O_XWPK = O_WPK  + 2ull*NGT*KTH*2*512;         // u16 98*8*2*512
constexpr size_t O_CPK  = O_XWPK + 2ull*NGT*KTX*2*512;         // u16 24*120*512
constexpr size_t O_SPK  = O_CPK  + 2ull*24*KTC*512;            // u16 4*12*2*512
constexpr size_t O_RPK  = O_SPK  + 2ull*4*KTH*2*512;           // u16 24*2*2*512
constexpr size_t O_BC   = O_RPK  + 2ull*24*2*2*512;            // f32 Gp
constexpr size_t O_WT   = O_BC + 4ull*Gp;                      // f32 Gp
constexpr size_t O_PRIV = (O_WT + 4ull*Gp + 255) & ~(size_t)255;
// per-block private region (stride PRIV_SZ):
constexpr size_t P_XWP  = 0;                                   // f32 [2][16][Gp]
constexpr size_t P_APK  = P_XWP + 4ull*2*16*Gp;                // u16 [120][512]
constexpr size_t P_TPK  = P_APK + 2ull*KTC*512;                // u16 [12][2][512]
constexpr size_t P_BUFH = P_TPK + 2ull*KTH*2*512;              // u16 [10][16][384]
constexpr size_t P_CF   = P_BUFH + 2ull*CSs*16*Hsz;            // f32 [16][384]
constexpr size_t P_HF   = P_CF + 4ull*16*Hsz;                  // f32 [16][384]
constexpr size_t PRIV_SZ = (P_HF + 4ull*16*Hsz + 255) & ~(size_t)255;
constexpr size_t O_XPK  = O_PRIV + PRIV_SZ * NRG;              // u16 [T][32][8][2][512]

__device__ __forceinline__ u16 f2bf(float f) {
    unsigned u = __float_as_uint(f);
    unsigned r = (u + 0x7FFFu + ((u >> 16) & 1u)) >> 16;
    return (u16)r;
}
__device__ __forceinline__ float bf2f(u16 v) {
    return __uint_as_float(((unsigned)v) << 16);
}
__device__ __forceinline__ float sigm(float v) { return 1.f / (1.f + expf(-v)); }

__global__ __launch_bounds__(256) void build_w(const float* __restrict__ kW,
                                               const float* __restrict__ kb,
                                               const float* __restrict__ rW,
                                               const float* __restrict__ rb,
                                               const float* __restrict__ sW,
                                               const float* __restrict__ rsW,
                                               u16* __restrict__ wpk,
                                               u16* __restrict__ xwpk,
                                               u16* __restrict__ spk,
                                               u16* __restrict__ rpk,
                                               float* __restrict__ bc,
                                               float* __restrict__ wt) {
    const int N1 = Gp * 384, N2 = Gp * 256, N3 = 64 * 384, N4 = 384 * 64;
    int idx = blockIdx.x * 256 + threadIdx.x;
    if (idx < N1) {
        int g = idx / 384, k = idx % 384;
        float v = (g < Gsz) ? rW[g * (Hsz + 1) + k] : 0.f;
        u16 hi = f2bf(v), lo = f2bf(v - bf2f(hi));
        size_t fo = ((size_t)((g >> 4) * KTH + (k >> 5)) * 2) * 512;
        int pos = ((g & 15) | (((k >> 3) & 3) << 4)) * 8 + (k & 7);
        wpk[fo + pos] = hi; wpk[fo + 512 + pos] = lo;
    } else if (idx < N1 + N2) {
        int i = idx - N1;
        int g = i / 256, k = i % 256;
        float v = (g < Gsz) ? kW[g * (Dsz + 1) + k] : 0.f;
        u16 hi = f2bf(v), lo = f2bf(v - bf2f(hi));
        size_t fo = ((size_t)((g >> 4) * KTX + (k >> 5)) * 2) * 512;
        int pos = ((g & 15) | (((k >> 3) & 3) << 4)) * 8 + (k & 7);
        xwpk[fo + pos] = hi; xwpk[fo + 512 + pos] = lo;
    } else if (idx < N1 + N2 + N3) {
        int i = idx - N1 - N2;
        int g = i / 384, k = i % 384;              // g<64
        float v = sW[g * Hsz + k];
        u16 hi = f2bf(v), lo = f2bf(v - bf2f(hi));
        size_t fo = ((size_t)((g >> 4) * KTH + (k >> 5)) * 2) * 512;
        int pos = ((g & 15) | (((k >> 3) & 3) << 4)) * 8 + (k & 7);
        spk[fo + pos] = hi; spk[fo + 512 + pos] = lo;
    } else if (idx < N1 + N2 + N3 + N4) {
        int i = idx - N1 - N2 - N3;
        int g = i / 64, k = i % 64;                // g<384
        float v = rsW[g * HSz + k];
        u16 hi = f2bf(v), lo = f2bf(v - bf2f(hi));
        size_t fo = ((size_t)((g >> 4) * 2 + (k >> 5)) * 2) * 512;
        int pos = ((g & 15) | (((k >> 3) & 3) << 4)) * 8 + (k & 7);
        rpk[fo + pos] = hi; rpk[fo + 512 + pos] = lo;
    } else if (idx < N1 + N2 + N3 + N4 + Gsz) {
        int g = idx - N1 - N2 - N3 - N4;
        bc[g] = kb[g] + rb[g];
        wt[g] = kW[g * (Dsz + 1) + Dsz] + rW[g * (Hsz + 1) + Hsz];
    }
}

__global__ __launch_bounds__(256) void pack_x(const float* __restrict__ x,
                                              u16* __restrict__ xpk) {
    int idx = blockIdx.x * 256 + threadIdx.x;
    int k = idx & 255, b = (idx >> 8) & 511, t = idx >> 17;
    float v = x[((size_t)b * Tsz + t) * Dsz + k];
    u16 hi = f2bf(v), lo = f2bf(v - bf2f(hi));
    size_t fo = (((size_t)t * 32 + (b >> 4)) * KTX + (k >> 5)) * 2 * 512;
    int pos = ((b & 15) | (((k >> 3) & 3) << 4)) * 8 + (k & 7);
    xpk[fo + pos] = hi;
    xpk[fo + 512 + pos] = lo;
}

__global__ __launch_bounds__(256) void pack_cw(const float* __restrict__ cW,
                                               u16* __restrict__ cpk) {
    int idx = blockIdx.x * 256 + threadIdx.x;
    if (idx >= Hsz * Hsz * CSs) return;
    int o = idx / (Hsz * CSs), k = idx % (Hsz * CSs);
    size_t fo = ((size_t)(o >> 4) * KTC + (k >> 5)) * 512;
    int pos = ((o & 15) | (((k >> 3) & 3) << 4)) * 8 + (k & 7);
    cpk[fo + pos] = f2bf(cW[idx]);
}

// One block = 16 batch rows, full T loop, no inter-block communication.
__global__ __launch_bounds__(512, 2) void persist(const float* __restrict__ tme,
                                                  const float* __restrict__ sb,
                                                  const float* __restrict__ rsb,
                                                  const float* __restrict__ cb,
                                                  char* __restrict__ ws,
                                                  float* __restrict__ out) {
    const u16* wpk  = (const u16*)(ws + O_WPK);
    const u16* xwpk = (const u16*)(ws + O_XWPK);
    const u16* cpk  = (const u16*)(ws + O_CPK);
    const u16* spk  = (const u16*)(ws + O_SPK);
    const u16* rpk  = (const u16*)(ws + O_RPK);
    const float* bc = (const float*)(ws + O_BC);
    const float* wt = (const float*)(ws + O_WT);
    const u16* xpk  = (const u16*)(ws + O_XPK);

    int rg = blockIdx.x;
    char* priv = ws + O_PRIV + (size_t)rg * PRIV_SZ;
    float* xwp  = (float*)(priv + P_XWP);
    u16*   apk  = (u16*)(priv + P_APK);
    u16*   tpk  = (u16*)(priv + P_TPK);
    u16*   bufh = (u16*)(priv + P_BUFH);
    float* cf   = (float*)(priv + P_CF);
    float* hf   = (float*)(priv + P_HF);

    float* out_last = out;
    float* out_seq  = out + (size_t)Bsz * Hsz;
    float* out_dist = out_seq + (size_t)Bsz * Tsz * Hsz;

    int tid = threadIdx.x;
    int wave = tid >> 6, lane = tid & 63, l15 = lane & 15, lk = lane >> 4;
    int b0 = rg * 16;

    __shared__ float s_xo[16][XOP];            // 100,864 B
    __shared__ u16   s_hpk[KTH][2][512];       // 24,576 B
    __shared__ float th1s[16][68];             // 4,352 B
    __shared__ float s_bufd[CSs][16];
    __shared__ float s_ld[16][CSs];
    __shared__ float s_fm[16][4], s_im[16][4];

    // -------- prologue: zero block-private state --------
    for (int i = tid; i < KTH * 2 * 256; i += 512) ((unsigned*)s_hpk)[i] = 0u;
    for (int i = tid; i < CSs * 16; i += 512) ((float*)s_bufd)[i] = 0.f;
    for (int i = tid; i < 16 * Hsz; i += 512) cf[i] = 0.f;
    for (int i = tid; i < CSs * 16 * Hsz / 2; i += 512) ((unsigned*)bufh)[i] = 0u;
    __syncthreads();

    auto xw_gemm = [&](int tt, float* dst) {
        const u16* xs = xpk + (((size_t)tt * 32 + rg) * KTX * 2) * 512;
        bf16x8 ah[KTX], al[KTX];
        #pragma unroll
        for (int kt = 0; kt < KTX; ++kt) {
            ah[kt] = *(const bf16x8*)(xs + (size_t)(kt * 2) * 512 + lane * 8);
            al[kt] = *(const bf16x8*)(xs + (size_t)(kt * 2 + 1) * 512 + lane * 8);
        }
        for (int g0 = 0; g0 < 3; ++g0) {
            f32x4 acc[4] = {};
            int gtb = wave + g0 * 32;
            #pragma unroll
            for (int kt = 0; kt < KTX; ++kt) {
                #pragma unroll
                for (int i = 0; i < 4; ++i) {
                    size_t fb = ((size_t)((gtb + 8 * i) * KTX + kt) * 2) * 512 + lane * 8;
                    bf16x8 bh = *(const bf16x8*)(xwpk + fb);
                    bf16x8 bl = *(const bf16x8*)(xwpk + fb + 512);
                    acc[i] = MFMA(ah[kt], bh, acc[i]);
                    acc[i] = MFMA(ah[kt], bl, acc[i]);
                    acc[i] = MFMA(al[kt], bh, acc[i]);
                }
            }
            #pragma unroll
            for (int i = 0; i < 4; ++i) {
                int col = (gtb + 8 * i) * 16 + l15;
                #pragma unroll
                for (int j = 0; j < 4; ++j)
                    dst[(lk * 4 + j) * Gp + col] = acc[i][j];
            }
        }
        if (wave < 2) {
            int gt = 96 + wave;
            f32x4 acc = {};
            #pragma unroll
            for (int kt = 0; kt < KTX; ++kt) {
                size_t fb = ((size_t)(gt * KTX + kt) * 2) * 512 + lane * 8;
                bf16x8 bh = *(const bf16x8*)(xwpk + fb);
                bf16x8 bl = *(const bf16x8*)(xwpk + fb + 512);
                acc = MFMA(ah[kt], bh, acc);
                acc = MFMA(ah[kt], bl, acc);
                acc = MFMA(al[kt], bh, acc);
            }
            int col = gt * 16 + l15;
            #pragma unroll
            for (int j = 0; j < 4; ++j)
                dst[(lk * 4 + j) * Gp + col] = acc[j];
        }
    };

    for (int t = 0; t <= Tsz; ++t) {
        f32x4 cacc[3] = {};   // conv(t-1) accumulators, live A -> B

        // ================= phase A: MFMA work =================
        if (t < Tsz) {
            if (t == 0) xw_gemm(0, xwp);           // bootstrap XW(0) -> slot 0
            {   // HW(t) = h(t-1) @ rW^T, + fold xw(t), -> s_xo
                bf16x8 ah[KTH], al[KTH];
                #pragma unroll
                for (int kt = 0; kt < KTH; ++kt) {
                    ah[kt] = *(const bf16x8*)&s_hpk[kt][0][lane * 8];
                    al[kt] = *(const bf16x8*)&s_hpk[kt][1][lane * 8];
                }
                const float* xwc = xwp + (size_t)(t & 1) * 16 * Gp;
                for (int g0 = 0; g0 < 3; ++g0) {
                    f32x4 acc[4] = {};
                    int gtb = wave + g0 * 32;
                    #pragma unroll
                    for (int kt = 0; kt < KTH; ++kt) {
                        #pragma unroll
                        for (int i = 0; i < 4; ++i) {
                            size_t fb = ((size_t)((gtb + 8 * i) * KTH + kt) * 2) * 512 + lane * 8;
                            bf16x8 bh = *(const bf16x8*)(wpk + fb);
                            bf16x8 bl = *(const bf16x8*)(wpk + fb + 512);
                            acc[i] = MFMA(ah[kt], bh, acc[i]);
                            acc[i] = MFMA(ah[kt], bl, acc[i]);
                            acc[i] = MFMA(al[kt], bh, acc[i]);
                        }
                    }
                    #pragma unroll
                    for (int i = 0; i < 4; ++i) {
                        int col = (gtb + 8 * i) * 16 + l15;
                        #pragma unroll
                        for (int j = 0; j < 4; ++j) {
                            int row = lk * 4 + j;
                            s_xo[row][col] = acc[i][j] + xwc[row * Gp + col];
                        }
                    }
                }
                if (wave < 2) {
                    int gt = 96 + wave;
                    f32x4 acc = {};
                    #pragma unroll
                    for (int kt = 0; kt < KTH; ++kt) {
                        size_t fb = ((size_t)(gt * KTH + kt) * 2) * 512 + lane * 8;
                        bf16x8 bh = *(const bf16x8*)(wpk + fb);
                        bf16x8 bl = *(const bf16x8*)(wpk + fb + 512);
                        acc = MFMA(ah[kt], bh, acc);
                        acc = MFMA(ah[kt], bl, acc);
                        acc = MFMA(al[kt], bh, acc);
                    }
                    int col = gt * 16 + l15;
                    #pragma unroll
                    for (int j = 0; j < 4; ++j)
                        s_xo[lk * 4 + j][col] = acc[j] + xwc[(lk * 4 + j) * Gp + col];
                }
            }
            if (t + 1 < Tsz)
                xw_gemm(t + 1, xwp + (size_t)((t + 1) & 1) * 16 * Gp);
        }
        if (t >= 1) {
            // CONV(t-1): A = apk (block-private), B = cpk; 3 o-tiles per wave
            for (int kt = 0; kt < KTC; ++kt) {
                bf16x8 a = *(const bf16x8*)(apk + (size_t)kt * 512 + lane * 8);
                #pragma unroll
                for (int i = 0; i < 3; ++i) {
                    int ot = wave * 3 + i;
                    bf16x8 b = *(const bf16x8*)(cpk + ((size_t)(ot * KTC + kt)) * 512 + lane * 8);
                    cacc[i] = MFMA(a, b, cacc[i]);
                }
            }
            // THEME stage 1 (waves 0..3): th1 = relu(thm @ sW^T + sb)
            if (wave < 4) {
                f32x4 a1 = {};
                for (int kt = 0; kt < KTH; ++kt) {
                    bf16x8 ah = *(const bf16x8*)(tpk + (size_t)(kt * 2) * 512 + lane * 8);
                    bf16x8 al = *(const bf16x8*)(tpk + (size_t)(kt * 2 + 1) * 512 + lane * 8);
                    size_t bb = ((size_t)(wave * KTH + kt) * 2) * 512 + lane * 8;
                    bf16x8 bh = *(const bf16x8*)(spk + bb);
                    bf16x8 bl = *(const bf16x8*)(spk + bb + 512);
                    a1 = MFMA(ah, bh, a1);
                    a1 = MFMA(ah, bl, a1);
                    a1 = MFMA(al, bh, a1);
                }
                int col = wave * 16 + l15;
                #pragma unroll
                for (int j = 0; j < 4; ++j)
                    th1s[lk * 4 + j][col] = fmaxf(a1[j] + sb[col], 0.f);
            }
        }
        __syncthreads();

        // ================= phase B: head + theme2/conv epilogue =================
        if (t < Tsz && tid < 16) {
            int r = tid, b = b0 + r;
            float tv = tme[b * Tsz + t];
            float zf[6];
            #pragma unroll
            for (int g = 0; g < 6; ++g)
                zf[g] = s_xo[r][g] + bc[g] + tv * wt[g];
            float m = fmaxf(zf[0], fmaxf(zf[1], zf[2]));
            float e0 = expf(zf[0] - m), e1 = expf(zf[1] - m), e2 = expf(zf[2] - m);
            float inv = 1.f / (e0 + e1 + e2);
            float p0 = e0 * inv, p1 = e1 * inv;
            s_fm[r][0] = p0; s_fm[r][1] = p0 + p1; s_fm[r][2] = 1.f;
            float mw = fmaxf(zf[3], fmaxf(zf[4], zf[5]));
            float f0 = expf(zf[3] - mw), f1 = expf(zf[4] - mw), f2 = expf(zf[5] - mw);
            float invw = 1.f / (f0 + f1 + f2);
            float q1 = f1 * invw, q2 = f2 * invw;
            s_im[r][0] = 1.f; s_im[r][1] = q1 + q2; s_im[r][2] = q2;
            float cd = 1.f - (p0 + (p0 + p1) + 1.f) * (1.f / 3.f);
            s_bufd[t % CSs][r] = cd;
            out_dist[(size_t)t * Bsz + b] = cd;
            float vals[CSs];
            float cum = 0.f;
            #pragma unroll
            for (int j = 0; j < CSs; ++j) {
                cum += s_bufd[(t + 1 + j) % CSs][r];
                vals[j] = cum;
            }
            float mx = vals[0];
            #pragma unroll
            for (int j = 1; j < CSs; ++j) mx = fmaxf(mx, vals[j]);
            float sum = 0.f;
            #pragma unroll
            for (int j = 0; j < CSs; ++j) { vals[j] = expf(vals[j] - mx); sum += vals[j]; }
            float invs = 1.f / sum;
            #pragma unroll
            for (int j = 0; j < CSs; ++j) s_ld[r][j] = vals[j] * invs;
        }
        if (t >= 1) {
            // THEME stage 2 + conv combine + epilogue(t-1)
            bf16x8 ah2[2], al2[2];
            #pragma unroll
            for (int kt = 0; kt < 2; ++kt) {
                bf16x8 zh, zl;
                #pragma unroll
                for (int e = 0; e < 8; ++e) {
                    float v = th1s[l15][kt * 32 + lk * 8 + e];
                    u16 hi = f2bf(v);
                    zh[e] = (short)hi;
                    zl[e] = (short)f2bf(v - bf2f(hi));
                }
                ah2[kt] = zh; al2[kt] = zl;
            }
            #pragma unroll
            for (int i = 0; i < 3; ++i) {
                int ot = wave * 3 + i;
                f32x4 a2 = {};
                #pragma unroll
                for (int kt = 0; kt < 2; ++kt) {
                    size_t bb = ((size_t)(ot * 2 + kt) * 2) * 512 + lane * 8;
                    bf16x8 bh = *(const bf16x8*)(rpk + bb);
                    bf16x8 bl = *(const bf16x8*)(rpk + bb + 512);
                    a2 = MFMA(ah2[kt], bh, a2);
                    a2 = MFMA(ah2[kt], bl, a2);
                    a2 = MFMA(al2[kt], bh, a2);
                }
                int col = ot * 16 + l15;
                #pragma unroll
                for (int j = 0; j < 4; ++j) {
                    int row = lk * 4 + j;
                    float convv = cacc[i][j] + cb[col];
                    float th = sigm(a2[j] + rsb[col]);
                    float val = th * convv + hf[row * Hsz + col];
                    out_seq[((size_t)(b0 + row) * Tsz + (t - 1)) * Hsz + col] = val;
                    if (t == Tsz) out_last[(size_t)(b0 + row) * Hsz + col] = val;
                }
            }
        }
        __syncthreads();

        // ================= phase C: cell(t) =================
        if (t < Tsz) {
            int r = tid >> 5;
            int c32 = tid & 31;
            int bb = b0 + r;
            float tv = tme[bb * Tsz + t];
            for (int i = 0; i < 12; ++i) {
                int ch = i * 32 + c32;
                int l = ch >> 7;
                float fm = s_fm[r][l], im = s_im[r][l];
                int g0 = 6 + ch, g1 = g0 + Hsz, g2 = g0 + 2 * Hsz, g3 = g0 + 3 * Hsz;
                float fg = sigm(s_xo[r][g0] + bc[g0] + tv * wt[g0]);
                float ig = sigm(s_xo[r][g1] + bc[g1] + tv * wt[g1]);
                float og = sigm(s_xo[r][g2] + bc[g2] + tv * wt[g2]);
                float ci = tanhf(s_xo[r][g3] + bc[g3] + tv * wt[g3]);
                float cl = cf[r * Hsz + ch];
                float ov = fm * im;
                float cn = ov * (fg * cl + ig * ci) + (fm - ov) * cl + (im - ov) * ci;
                float hn = og * tanhf(cn);
                cf[r * Hsz + ch] = cn;
                hf[r * Hsz + ch] = hn;
                u16 hh = f2bf(hn);
                u16 hl = f2bf(hn - bf2f(hh));
                int pos = (r | (((ch >> 3) & 3) << 4)) * 8 + (ch & 7);
                s_hpk[ch >> 5][0][pos] = hh;
                s_hpk[ch >> 5][1][pos] = hl;
                bufh[((t % CSs) * 16 + r) * Hsz + ch] = hh;
                float acc = 0.f;
                #pragma unroll
                for (int j = 0; j < CSs; ++j) {
                    int slot = (t + 1 + j) % CSs;
                    float v = (j == CSs - 1) ? hn
                                             : bf2f(bufh[(slot * 16 + r) * Hsz + ch]);
                    float av = v * s_ld[r][j];
                    int k = ch * CSs + j;
                    int pp = (r | (((k >> 3) & 3) << 4)) * 8 + (k & 7);
                    apk[(size_t)(k >> 5) * 512 + pp] = f2bf(av);
                    acc += av;
                }
                float thm = acc * 0.1f;
                u16 th = f2bf(thm), tl = f2bf(thm - bf2f(th));
                tpk[(size_t)((ch >> 5) * 2) * 512 + pos] = th;
                tpk[(size_t)((ch >> 5) * 2 + 1) * 512 + pos] = tl;
            }
        }
        __syncthreads();
    }
}

extern "C" void kernel_launch(void* const* d_in, const int* in_sizes, int n_in,
                              void* d_out, int out_size, void* d_ws, size_t ws_size,
                              hipStream_t stream) {
    const float* x   = (const float*)d_in[0];
    const float* tme = (const float*)d_in[1];
    const float* kW  = (const float*)d_in[2];
    const float* kb  = (const float*)d_in[3];
    const float* rW  = (const float*)d_in[4];
    const float* rb  = (const float*)d_in[5];
    const float* sW  = (const float*)d_in[6];
    const float* sb  = (const float*)d_in[7];
    const float* rsW = (const float*)d_in[8];
    const float* rsb = (const float*)d_in[9];
    const float* cW  = (const float*)d_in[10];
    const float* cb  = (const float*)d_in[11];

    char* wsb = (char*)d_ws;
    float* outp = (float*)d_out;

    u16* wpk  = (u16*)(wsb + O_WPK);
    u16* xwpk = (u16*)(wsb + O_XWPK);
    u16* cpk  = (u16*)(wsb + O_CPK);
    u16* spk  = (u16*)(wsb + O_SPK);
    u16* rpk  = (u16*)(wsb + O_RPK);
    float* bc = (float*)(wsb + O_BC);
    float* wt = (float*)(wsb + O_WT);
    u16* xpk  = (u16*)(wsb + O_XPK);

    {
        int nW = Gp * 384 + Gp * 256 + 64 * 384 + 384 * 64 + Gsz;
        build_w<<<(nW + 255) / 256, 256, 0, stream>>>(kW, kb, rW, rb, sW, rsW,
                                                      wpk, xwpk, spk, rpk, bc, wt);
    }
    pack_x<<<(Tsz * Bsz * Dsz) / 256, 256, 0, stream>>>(x, xpk);
    pack_cw<<<(Hsz * Hsz * CSs + 255) / 256, 256, 0, stream>>>(cW, cpk);

    persist<<<NRG, 512, 0, stream>>>(tme, sb, rsb, cb, wsb, outp);
}

// Round 10
// 16520.421 us; speedup vs baseline: 1.9498x; 1.9498x over previous
//
#include <hip/hip_runtime.h>
#include <math.h>

typedef unsigned short u16;
typedef __attribute__((ext_vector_type(8))) short bf16x8;
typedef __attribute__((ext_vector_type(4))) float f32x4;

#define MFMA(a, b, c) __builtin_amdgcn_mfma_f32_16x16x32_bf16(a, b, c, 0, 0, 0)

#define Bsz 512
#define Tsz 128
#define Dsz 256
#define CSs 10
#define Hsz 384
#define Gsz 1542
#define HSz 64
#define Gp  1568
#define NGT 98       // Gp/16
#define KTH 12       // 384/32
#define KTX 8        // 256/32
#define KTC 120      // 3840/32
#define NRG 32       // scan blocks, 16 batch rows each
#define XOP 1576     // s_xo row stride (floats)

// ---------------- ws layout (byte offsets) ----------------
constexpr size_t O_WPK  = 0;                                   // u16 98*12*2*512
constexpr size_t O_XWPK = O_WPK  + 2ull*NGT*KTH*2*512;         // u16 98*8*2*512
constexpr size_t O_CPK  = O_XWPK + 2ull*NGT*KTX*2*512;         // u16 24*120*512
constexpr size_t O_SPK  = O_CPK  + 2ull*24*KTC*512;            // u16 4*12*2*512
constexpr size_t O_RPK  = O_SPK  + 2ull*4*KTH*2*512;           // u16 24*2*2*512
constexpr size_t O_BC   = O_RPK  + 2ull*24*2*2*512;            // f32 Gp
constexpr size_t O_WT   = O_BC + 4ull*Gp;                      // f32 Gp
constexpr size_t O_XWPB = (O_WT + 4ull*Gp + 255) & ~(size_t)255;
constexpr size_t XWP_SZ = 4ull*2*16*Gp;                        // per-block xw dbuf
constexpr size_t O_HBF  = O_XWPB + XWP_SZ*NRG;                 // u16 B*T*H (50 MB)
constexpr size_t O_XPK  = O_HBF + 2ull*Bsz*Tsz*Hsz;            // u16 (67 MB)

__device__ __forceinline__ u16 f2bf(float f) {
    unsigned u = __float_as_uint(f);
    unsigned r = (u + 0x7FFFu + ((u >> 16) & 1u)) >> 16;
    return (u16)r;
}
__device__ __forceinline__ float bf2f(u16 v) {
    return __uint_as_float(((unsigned)v) << 16);
}
__device__ __forceinline__ float sigm(float v) { return 1.f / (1.f + expf(-v)); }

__global__ __launch_bounds__(256) void build_w(const float* __restrict__ kW,
                                               const float* __restrict__ kb,
                                               const float* __restrict__ rW,
                                               const float* __restrict__ rb,
                                               const float* __restrict__ sW,
                                               const float* __restrict__ rsW,
                                               u16* __restrict__ wpk,
                                               u16* __restrict__ xwpk,
                                               u16* __restrict__ spk,
                                               u16* __restrict__ rpk,
                                               float* __restrict__ bc,
                                               float* __restrict__ wt) {
    const int N1 = Gp * 384, N2 = Gp * 256, N3 = 64 * 384, N4 = 384 * 64;
    int idx = blockIdx.x * 256 + threadIdx.x;
    if (idx < N1) {
        int g = idx / 384, k = idx % 384;
        float v = (g < Gsz) ? rW[g * (Hsz + 1) + k] : 0.f;
        u16 hi = f2bf(v), lo = f2bf(v - bf2f(hi));
        size_t fo = ((size_t)((g >> 4) * KTH + (k >> 5)) * 2) * 512;
        int pos = ((g & 15) | (((k >> 3) & 3) << 4)) * 8 + (k & 7);
        wpk[fo + pos] = hi; wpk[fo + 512 + pos] = lo;
    } else if (idx < N1 + N2) {
        int i = idx - N1;
        int g = i / 256, k = i % 256;
        float v = (g < Gsz) ? kW[g * (Dsz + 1) + k] : 0.f;
        u16 hi = f2bf(v), lo = f2bf(v - bf2f(hi));
        size_t fo = ((size_t)((g >> 4) * KTX + (k >> 5)) * 2) * 512;
        int pos = ((g & 15) | (((k >> 3) & 3) << 4)) * 8 + (k & 7);
        xwpk[fo + pos] = hi; xwpk[fo + 512 + pos] = lo;
    } else if (idx < N1 + N2 + N3) {
        int i = idx - N1 - N2;
        int g = i / 384, k = i % 384;              // g<64
        float v = sW[g * Hsz + k];
        u16 hi = f2bf(v), lo = f2bf(v - bf2f(hi));
        size_t fo = ((size_t)((g >> 4) * KTH + (k >> 5)) * 2) * 512;
        int pos = ((g & 15) | (((k >> 3) & 3) << 4)) * 8 + (k & 7);
        spk[fo + pos] = hi; spk[fo + 512 + pos] = lo;
    } else if (idx < N1 + N2 + N3 + N4) {
        int i = idx - N1 - N2 - N3;
        int g = i / 64, k = i % 64;                // g<384
        float v = rsW[g * HSz + k];
        u16 hi = f2bf(v), lo = f2bf(v - bf2f(hi));
        size_t fo = ((size_t)((g >> 4) * 2 + (k >> 5)) * 2) * 512;
        int pos = ((g & 15) | (((k >> 3) & 3) << 4)) * 8 + (k & 7);
        rpk[fo + pos] = hi; rpk[fo + 512 + pos] = lo;
    } else if (idx < N1 + N2 + N3 + N4 + Gsz) {
        int g = idx - N1 - N2 - N3 - N4;
        bc[g] = kb[g] + rb[g];
        wt[g] = kW[g * (Dsz + 1) + Dsz] + rW[g * (Hsz + 1) + Hsz];
    }
}

__global__ __launch_bounds__(256) void pack_x(const float* __restrict__ x,
                                              u16* __restrict__ xpk) {
    int idx = blockIdx.x * 256 + threadIdx.x;
    int k = idx & 255, b = (idx >> 8) & 511, t = idx >> 17;
    float v = x[((size_t)b * Tsz + t) * Dsz + k];
    u16 hi = f2bf(v), lo = f2bf(v - bf2f(hi));
    size_t fo = (((size_t)t * 32 + (b >> 4)) * KTX + (k >> 5)) * 2 * 512;
    int pos = ((b & 15) | (((k >> 3) & 3) << 4)) * 8 + (k & 7);
    xpk[fo + pos] = hi;
    xpk[fo + 512 + pos] = lo;
}

__global__ __launch_bounds__(256) void pack_cw(const float* __restrict__ cW,
                                               u16* __restrict__ cpk) {
    int idx = blockIdx.x * 256 + threadIdx.x;
    if (idx >= Hsz * Hsz * CSs) return;
    int o = idx / (Hsz * CSs), k = idx % (Hsz * CSs);
    size_t fo = ((size_t)(o >> 4) * KTC + (k >> 5)) * 512;
    int pos = ((o & 15) | (((k >> 3) & 3) << 4)) * 8 + (k & 7);
    cpk[fo + pos] = f2bf(cW[idx]);
}

// ---- phase 1: serial recurrence only. 32 blocks x 16 rows, no conv/theme. ----
__global__ __launch_bounds__(512, 1) void scan(const float* __restrict__ tme,
                                               char* __restrict__ ws,
                                               float* __restrict__ out) {
    const u16* wpk  = (const u16*)(ws + O_WPK);
    const u16* xwpk = (const u16*)(ws + O_XWPK);
    const float* bc = (const float*)(ws + O_BC);
    const float* wt = (const float*)(ws + O_WT);
    const u16* xpk  = (const u16*)(ws + O_XPK);

    int rg = blockIdx.x;
    float* xwp = (float*)(ws + O_XWPB + (size_t)rg * XWP_SZ);
    u16*   hbf = (u16*)(ws + O_HBF);

    float* out_seq  = out + (size_t)Bsz * Hsz;
    float* out_dist = out_seq + (size_t)Bsz * Tsz * Hsz;

    int tid = threadIdx.x;
    int wave = tid >> 6, lane = tid & 63, l15 = lane & 15, lk = lane >> 4;
    int b0 = rg * 16;

    __shared__ float s_xo[16][XOP];            // 100,864 B
    __shared__ u16   s_hpk[KTH][2][512];       // 24,576 B
    __shared__ float s_cf[16][Hsz];            // 24,576 B

    for (int i = tid; i < KTH * 2 * 256; i += 512) ((unsigned*)s_hpk)[i] = 0u;
    for (int i = tid; i < 16 * Hsz; i += 512) ((float*)s_cf)[i] = 0.f;
    __syncthreads();

    auto xw_gemm = [&](int tt, float* dst) {
        const u16* xs = xpk + (((size_t)tt * 32 + rg) * KTX * 2) * 512;
        bf16x8 ah[KTX], al[KTX];
        #pragma unroll
        for (int kt = 0; kt < KTX; ++kt) {
            ah[kt] = *(const bf16x8*)(xs + (size_t)(kt * 2) * 512 + lane * 8);
            al[kt] = *(const bf16x8*)(xs + (size_t)(kt * 2 + 1) * 512 + lane * 8);
        }
        for (int g0 = 0; g0 < 3; ++g0) {
            f32x4 acc[4] = {};
            int gtb = wave + g0 * 32;
            #pragma unroll
            for (int kt = 0; kt < KTX; ++kt) {
                #pragma unroll
                for (int i = 0; i < 4; ++i) {
                    size_t fb = ((size_t)((gtb + 8 * i) * KTX + kt) * 2) * 512 + lane * 8;
                    bf16x8 bh = *(const bf16x8*)(xwpk + fb);
                    bf16x8 bl = *(const bf16x8*)(xwpk + fb + 512);
                    acc[i] = MFMA(ah[kt], bh, acc[i]);
                    acc[i] = MFMA(ah[kt], bl, acc[i]);
                    acc[i] = MFMA(al[kt], bh, acc[i]);
                }
            }
            #pragma unroll
            for (int i = 0; i < 4; ++i) {
                int col = (gtb + 8 * i) * 16 + l15;
                #pragma unroll
                for (int j = 0; j < 4; ++j)
                    dst[(lk * 4 + j) * Gp + col] = acc[i][j];
            }
        }
        if (wave < 2) {
            int gt = 96 + wave;
            f32x4 acc = {};
            #pragma unroll
            for (int kt = 0; kt < KTX; ++kt) {
                size_t fb = ((size_t)(gt * KTX + kt) * 2) * 512 + lane * 8;
                bf16x8 bh = *(const bf16x8*)(xwpk + fb);
                bf16x8 bl = *(const bf16x8*)(xwpk + fb + 512);
                acc = MFMA(ah[kt], bh, acc);
                acc = MFMA(ah[kt], bl, acc);
                acc = MFMA(al[kt], bh, acc);
            }
            int col = gt * 16 + l15;
            #pragma unroll
            for (int j = 0; j < 4; ++j)
                dst[(lk * 4 + j) * Gp + col] = acc[j];
        }
    };

    xw_gemm(0, xwp);       // bootstrap XW(0) into slot 0
    __syncthreads();

    for (int t = 0; t < Tsz; ++t) {
        // ---- phase A: HW(t) = h(t-1)@rW^T (+xw fold) -> s_xo; XW(t+1) prefetch ----
        {
            bf16x8 ah[KTH], al[KTH];
            #pragma unroll
            for (int kt = 0; kt < KTH; ++kt) {
                ah[kt] = *(const bf16x8*)&s_hpk[kt][0][lane * 8];
                al[kt] = *(const bf16x8*)&s_hpk[kt][1][lane * 8];
            }
            const float* xwc = xwp + (size_t)(t & 1) * 16 * Gp;
            for (int g0 = 0; g0 < 3; ++g0) {
                f32x4 acc[4] = {};
                int gtb = wave + g0 * 32;
                #pragma unroll
                for (int kt = 0; kt < KTH; ++kt) {
                    #pragma unroll
                    for (int i = 0; i < 4; ++i) {
                        size_t fb = ((size_t)((gtb + 8 * i) * KTH + kt) * 2) * 512 + lane * 8;
                        bf16x8 bh = *(const bf16x8*)(wpk + fb);
                        bf16x8 bl = *(const bf16x8*)(wpk + fb + 512);
                        acc[i] = MFMA(ah[kt], bh, acc[i]);
                        acc[i] = MFMA(ah[kt], bl, acc[i]);
                        acc[i] = MFMA(al[kt], bh, acc[i]);
                    }
                }
                #pragma unroll
                for (int i = 0; i < 4; ++i) {
                    int col = (gtb + 8 * i) * 16 + l15;
                    #pragma unroll
                    for (int j = 0; j < 4; ++j) {
                        int row = lk * 4 + j;
                        s_xo[row][col] = acc[i][j] + xwc[row * Gp + col];
                    }
                }
            }
            if (wave < 2) {
                int gt = 96 + wave;
                f32x4 acc = {};
                #pragma unroll
                for (int kt = 0; kt < KTH; ++kt) {
                    size_t fb = ((size_t)(gt * KTH + kt) * 2) * 512 + lane * 8;
                    bf16x8 bh = *(const bf16x8*)(wpk + fb);
                    bf16x8 bl = *(const bf16x8*)(wpk + fb + 512);
                    acc = MFMA(ah[kt], bh, acc);
                    acc = MFMA(ah[kt], bl, acc);
                    acc = MFMA(al[kt], bh, acc);
                }
                int col = gt * 16 + l15;
                #pragma unroll
                for (int j = 0; j < 4; ++j)
                    s_xo[lk * 4 + j][col] = acc[j] + xwc[(lk * 4 + j) * Gp + col];
            }
        }
        if (t + 1 < Tsz)
            xw_gemm(t + 1, xwp + (size_t)((t + 1) & 1) * 16 * Gp);
        __syncthreads();

        // ---- cell(t): gates + c/h update; h -> LDS frag + globals ----
        {
            int r = tid >> 5, c32 = tid & 31;
            int b = b0 + r;
            float tv = tme[b * Tsz + t];
            float zf[6];
            #pragma unroll
            for (int g = 0; g < 6; ++g)
                zf[g] = s_xo[r][g] + bc[g] + tv * wt[g];
            float m = fmaxf(zf[0], fmaxf(zf[1], zf[2]));
            float e0 = expf(zf[0] - m), e1 = expf(zf[1] - m), e2 = expf(zf[2] - m);
            float inv = 1.f / (e0 + e1 + e2);
            float fm0 = e0 * inv, fm1 = fm0 + e1 * inv;
            float mw = fmaxf(zf[3], fmaxf(zf[4], zf[5]));
            float f0 = expf(zf[3] - mw), f1 = expf(zf[4] - mw), f2 = expf(zf[5] - mw);
            float invw = 1.f / (f0 + f1 + f2);
            float im2 = f2 * invw, im1 = f1 * invw + im2;
            if (c32 == 0)
                out_dist[(size_t)t * Bsz + b] = 1.f - (fm0 + fm1 + 1.f) * (1.f / 3.f);
            #pragma unroll
            for (int i = 0; i < 12; ++i) {
                int ch = i * 32 + c32;
                const int l = i >> 2;                 // compile-time per unrolled i
                float fm = (l == 0) ? fm0 : ((l == 1) ? fm1 : 1.f);
                float im = (l == 0) ? 1.f : ((l == 1) ? im1 : im2);
                int g0 = 6 + ch, g1 = g0 + Hsz, g2 = g0 + 2 * Hsz, g3 = g0 + 3 * Hsz;
                float fg = sigm(s_xo[r][g0] + bc[g0] + tv * wt[g0]);
                float ig = sigm(s_xo[r][g1] + bc[g1] + tv * wt[g1]);
                float og = sigm(s_xo[r][g2] + bc[g2] + tv * wt[g2]);
                float ci = tanhf(s_xo[r][g3] + bc[g3] + tv * wt[g3]);
                float cl = s_cf[r][ch];
                float ov = fm * im;
                float cn = ov * (fg * cl + ig * ci) + (fm - ov) * cl + (im - ov) * ci;
                float hn = og * tanhf(cn);
                s_cf[r][ch] = cn;
                u16 hh = f2bf(hn);
                u16 hl = f2bf(hn - bf2f(hh));
                int pos = (r | (((ch >> 3) & 3) << 4)) * 8 + (ch & 7);
                s_hpk[ch >> 5][0][pos] = hh;
                s_hpk[ch >> 5][1][pos] = hl;
                size_t oi = ((size_t)b * Tsz + t) * Hsz + ch;
                out_seq[oi] = hn;          // h (f32) — post adds theme*conv
                hbf[oi] = hh;              // h (bf16) for conv A-build
            }
        }
        __syncthreads();
    }
}

// ---- phase 2: fully parallel over (b, t). Block = (b, 16 t's). ----
__global__ __launch_bounds__(512, 1) void post(const float* __restrict__ sb,
                                               const float* __restrict__ rsb,
                                               const float* __restrict__ cb,
                                               char* __restrict__ ws,
                                               float* __restrict__ out) {
    const u16* cpk = (const u16*)(ws + O_CPK);
    const u16* spk = (const u16*)(ws + O_SPK);
    const u16* rpk = (const u16*)(ws + O_RPK);
    const u16* hbf = (const u16*)(ws + O_HBF);

    float* out_last = out;
    float* out_seq  = out + (size_t)Bsz * Hsz;
    const float* out_dist = out_seq + (size_t)Bsz * Tsz * Hsz;

    int b = blockIdx.x, t0 = blockIdx.y * 16;
    int tid = threadIdx.x;
    int wave = tid >> 6, lane = tid & 63, l15 = lane & 15, lk = lane >> 4;

    __shared__ u16 s_apk[KTC][512];            // 122,880 B
    __shared__ u16 s_tpk[KTH * 2][512];        // 24,576 B
    __shared__ float th1s[16][68];
    __shared__ float s_ld[16][CSs];

    if (tid < 16) {
        int r = tid;
        float vals[CSs];
        float cum = 0.f;
        #pragma unroll
        for (int j = 0; j < CSs; ++j) {
            int tp = t0 + r - 9 + j;
            float d = (tp < 0) ? 0.f : out_dist[(size_t)tp * Bsz + b];
            cum += d;
            vals[j] = cum;
        }
        float mx = vals[0];
        #pragma unroll
        for (int j = 1; j < CSs; ++j) mx = fmaxf(mx, vals[j]);
        float sum = 0.f;
        #pragma unroll
        for (int j = 0; j < CSs; ++j) { vals[j] = expf(vals[j] - mx); sum += vals[j]; }
        float invs = 1.f / sum;
        #pragma unroll
        for (int j = 0; j < CSs; ++j) s_ld[r][j] = vals[j] * invs;
    }
    __syncthreads();

    // A-build: av[r][k=ch*10+j] = h(b,t0+r-9+j)[ch] * ld[r][j]; thm = mean_j
    for (int u = tid; u < 768; u += 512) {
        int r = u / 48, c8 = u % 48, ch0 = c8 * 8;
        float acc[8] = {0.f, 0.f, 0.f, 0.f, 0.f, 0.f, 0.f, 0.f};
        #pragma unroll
        for (int j = 0; j < CSs; ++j) {
            int tp = t0 + r - 9 + j;
            float ldv = s_ld[r][j];
            if (tp >= 0) {
                bf16x8 hv = *(const bf16x8*)(hbf + ((size_t)b * Tsz + tp) * Hsz + ch0);
                #pragma unroll
                for (int e = 0; e < 8; ++e) {
                    float av = bf2f((u16)hv[e]) * ldv;
                    int k = (ch0 + e) * CSs + j;
                    s_apk[k >> 5][(r | (((k >> 3) & 3) << 4)) * 8 + (k & 7)] = f2bf(av);
                    acc[e] += av;
                }
            } else {
                #pragma unroll
                for (int e = 0; e < 8; ++e) {
                    int k = (ch0 + e) * CSs + j;
                    s_apk[k >> 5][(r | (((k >> 3) & 3) << 4)) * 8 + (k & 7)] = 0;
                }
            }
        }
        int pos0 = (r | (((ch0 >> 3) & 3) << 4)) * 8;
        int kt2 = (ch0 >> 5) * 2;
        #pragma unroll
        for (int e = 0; e < 8; ++e) {
            float thm = acc[e] * 0.1f;
            u16 th = f2bf(thm), tl = f2bf(thm - bf2f(th));
            s_tpk[kt2][pos0 + e] = th;
            s_tpk[kt2 + 1][pos0 + e] = tl;
        }
    }
    __syncthreads();

    // conv MFMA (24 ot over 8 waves) + theme stage 1 (waves 0-3)
    f32x4 cacc[3] = {};
    for (int kt = 0; kt < KTC; ++kt) {
        bf16x8 a = *(const bf16x8*)&s_apk[kt][lane * 8];
        #pragma unroll
        for (int i = 0; i < 3; ++i) {
            int ot = wave * 3 + i;
            bf16x8 bv = *(const bf16x8*)(cpk + ((size_t)(ot * KTC + kt)) * 512 + lane * 8);
            cacc[i] = MFMA(a, bv, cacc[i]);
        }
    }
    if (wave < 4) {
        f32x4 a1 = {};
        for (int kt = 0; kt < KTH; ++kt) {
            bf16x8 ah = *(const bf16x8*)&s_tpk[kt * 2][lane * 8];
            bf16x8 al = *(const bf16x8*)&s_tpk[kt * 2 + 1][lane * 8];
            size_t bb = ((size_t)(wave * KTH + kt) * 2) * 512 + lane * 8;
            bf16x8 bh = *(const bf16x8*)(spk + bb);
            bf16x8 bl = *(const bf16x8*)(spk + bb + 512);
            a1 = MFMA(ah, bh, a1);
            a1 = MFMA(ah, bl, a1);
            a1 = MFMA(al, bh, a1);
        }
        int col = wave * 16 + l15;
        #pragma unroll
        for (int j = 0; j < 4; ++j)
            th1s[lk * 4 + j][col] = fmaxf(a1[j] + sb[col], 0.f);
    }
    __syncthreads();

    // theme stage 2 + epilogue: out = sigm(mlp)*(conv+cb) + h  (h already in out_seq)
    bf16x8 ah2[2], al2[2];
    #pragma unroll
    for (int kt = 0; kt < 2; ++kt) {
        bf16x8 zh, zl;
        #pragma unroll
        for (int e = 0; e < 8; ++e) {
            float v = th1s[l15][kt * 32 + lk * 8 + e];
            u16 hi = f2bf(v);
            zh[e] = (short)hi;
            zl[e] = (short)f2bf(v - bf2f(hi));
        }
        ah2[kt] = zh; al2[kt] = zl;
    }
    #pragma unroll
    for (int i = 0; i < 3; ++i) {
        int ot = wave * 3 + i;
        f32x4 a2 = {};
        #pragma unroll
        for (int kt = 0; kt < 2; ++kt) {
            size_t bb = ((size_t)(ot * 2 + kt) * 2) * 512 + lane * 8;
            bf16x8 bh = *(const bf16x8*)(rpk + bb);
            bf16x8 bl = *(const bf16x8*)(rpk + bb + 512);
            a2 = MFMA(ah2[kt], bh, a2);
            a2 = MFMA(ah2[kt], bl, a2);
            a2 = MFMA(al2[kt], bh, a2);
        }
        int col = ot * 16 + l15;
        #pragma unroll
        for (int j = 0; j < 4; ++j) {
            int row = lk * 4 + j;
            int tt = t0 + row;
            size_t oi = ((size_t)b * Tsz + tt) * Hsz + col;
            float convv = cacc[i][j] + cb[col];
            float th = sigm(a2[j] + rsb[col]);
            float val = th * convv + out_seq[oi];
            out_seq[oi] = val;
            if (tt == Tsz - 1) out_last[(size_t)b * Hsz + col] = val;
        }
    }
}

extern "C" void kernel_launch(void* const* d_in, const int* in_sizes, int n_in,
                              void* d_out, int out_size, void* d_ws, size_t ws_size,
                              hipStream_t stream) {
    const float* x   = (const float*)d_in[0];
    const float* tme = (const float*)d_in[1];
    const float* kW  = (const float*)d_in[2];
    const float* kb  = (const float*)d_in[3];
    const float* rW  = (const float*)d_in[4];
    const float* rb  = (const float*)d_in[5];
    const float* sW  = (const float*)d_in[6];
    const float* sb  = (const float*)d_in[7];
    const float* rsW = (const float*)d_in[8];
    const float* rsb = (const float*)d_in[9];
    const float* cW  = (const float*)d_in[10];
    const float* cb  = (const float*)d_in[11];

    char* wsb = (char*)d_ws;
    float* outp = (float*)d_out;

    u16* wpk  = (u16*)(wsb + O_WPK);
    u16* xwpk = (u16*)(wsb + O_XWPK);
    u16* cpk  = (u16*)(wsb + O_CPK);
    u16* spk  = (u16*)(wsb + O_SPK);
    u16* rpk  = (u16*)(wsb + O_RPK);
    float* bc = (float*)(wsb + O_BC);
    float* wt = (float*)(wsb + O_WT);
    u16* xpk  = (u16*)(wsb + O_XPK);

    {
        int nW = Gp * 384 + Gp * 256 + 64 * 384 + 384 * 64 + Gsz;
        build_w<<<(nW + 255) / 256, 256, 0, stream>>>(kW, kb, rW, rb, sW, rsW,
                                                      wpk, xwpk, spk, rpk, bc, wt);
    }
    pack_x<<<(Tsz * Bsz * Dsz) / 256, 256, 0, stream>>>(x, xpk);
    pack_cw<<<(Hsz * Hsz * CSs + 255) / 256, 256, 0, stream>>>(cW, cpk);

    scan<<<NRG, 512, 0, stream>>>(tme, wsb, outp);
    post<<<dim3(Bsz, Tsz / 16), 512, 0, stream>>>(sb, rsb, cb, wsb, outp);
}

// Round 12
// 15736.459 us; speedup vs baseline: 2.0469x; 1.0498x over previous
//
#include <hip/hip_runtime.h>
#include <math.h>

typedef unsigned short u16;
typedef __attribute__((ext_vector_type(8))) short bf16x8;
typedef __attribute__((ext_vector_type(4))) float f32x4;

#define MFMA(a, b, c) __builtin_amdgcn_mfma_f32_16x16x32_bf16(a, b, c, 0, 0, 0)

#define Bsz 512
#define Tsz 128
#define Dsz 256
#define CSs 10
#define Hsz 384
#define Gsz 1542
#define HSz 64
#define Gp  1568
#define NGT 98       // Gp/16
#define KTH 12       // 384/32
#define KTX 8        // 256/32
#define KTC 120      // 3840/32
#define NRG 32       // scan blocks, 16 batch rows each
#define XOP 1580     // s_xo row stride (floats): 1580%32=12 -> 2-way banks (free)

// ---------------- ws layout (byte offsets) ----------------
constexpr size_t O_WPK  = 0;                                   // u16 98*12*2*512
constexpr size_t O_XWPK = O_WPK  + 2ull*NGT*KTH*2*512;         // u16 98*8*2*512
constexpr size_t O_CPK  = O_XWPK + 2ull*NGT*KTX*2*512;         // u16 24*120*512
constexpr size_t O_SPK  = O_CPK  + 2ull*24*KTC*512;            // u16 4*12*2*512
constexpr size_t O_RPK  = O_SPK  + 2ull*4*KTH*2*512;           // u16 24*2*2*512
constexpr size_t O_BC   = O_RPK  + 2ull*24*2*2*512;            // f32 Gp
constexpr size_t O_WT   = O_BC + 4ull*Gp;                      // f32 Gp
constexpr size_t O_HBF  = (O_WT + 4ull*Gp + 255) & ~(size_t)255;  // u16 B*T*H (50 MB)
constexpr size_t O_XPK  = O_HBF + 2ull*Bsz*Tsz*Hsz;            // u16 (67 MB)

__device__ __forceinline__ u16 f2bf(float f) {
    unsigned u = __float_as_uint(f);
    unsigned r = (u + 0x7FFFu + ((u >> 16) & 1u)) >> 16;
    return (u16)r;
}
__device__ __forceinline__ float bf2f(u16 v) {
    return __uint_as_float(((unsigned)v) << 16);
}
__device__ __forceinline__ float sigm(float v) { return 1.f / (1.f + expf(-v)); }

__global__ __launch_bounds__(256) void build_w(const float* __restrict__ kW,
                                               const float* __restrict__ kb,
                                               const float* __restrict__ rW,
                                               const float* __restrict__ rb,
                                               const float* __restrict__ sW,
                                               const float* __restrict__ rsW,
                                               u16* __restrict__ wpk,
                                               u16* __restrict__ xwpk,
                                               u16* __restrict__ spk,
                                               u16* __restrict__ rpk,
                                               float* __restrict__ bc,
                                               float* __restrict__ wt) {
    const int N1 = Gp * 384, N2 = Gp * 256, N3 = 64 * 384, N4 = 384 * 64;
    int idx = blockIdx.x * 256 + threadIdx.x;
    if (idx < N1) {
        int g = idx / 384, k = idx % 384;
        float v = (g < Gsz) ? rW[g * (Hsz + 1) + k] : 0.f;
        u16 hi = f2bf(v), lo = f2bf(v - bf2f(hi));
        size_t fo = ((size_t)((g >> 4) * KTH + (k >> 5)) * 2) * 512;
        int pos = ((g & 15) | (((k >> 3) & 3) << 4)) * 8 + (k & 7);
        wpk[fo + pos] = hi; wpk[fo + 512 + pos] = lo;
    } else if (idx < N1 + N2) {
        int i = idx - N1;
        int g = i / 256, k = i % 256;
        float v = (g < Gsz) ? kW[g * (Dsz + 1) + k] : 0.f;
        u16 hi = f2bf(v), lo = f2bf(v - bf2f(hi));
        size_t fo = ((size_t)((g >> 4) * KTX + (k >> 5)) * 2) * 512;
        int pos = ((g & 15) | (((k >> 3) & 3) << 4)) * 8 + (k & 7);
        xwpk[fo + pos] = hi; xwpk[fo + 512 + pos] = lo;
    } else if (idx < N1 + N2 + N3) {
        int i = idx - N1 - N2;
        int g = i / 384, k = i % 384;              // g<64
        float v = sW[g * Hsz + k];
        u16 hi = f2bf(v), lo = f2bf(v - bf2f(hi));
        size_t fo = ((size_t)((g >> 4) * KTH + (k >> 5)) * 2) * 512;
        int pos = ((g & 15) | (((k >> 3) & 3) << 4)) * 8 + (k & 7);
        spk[fo + pos] = hi; spk[fo + 512 + pos] = lo;
    } else if (idx < N1 + N2 + N3 + N4) {
        int i = idx - N1 - N2 - N3;
        int g = i / 64, k = i % 64;                // g<384
        float v = rsW[g * HSz + k];
        u16 hi = f2bf(v), lo = f2bf(v - bf2f(hi));
        size_t fo = ((size_t)((g >> 4) * 2 + (k >> 5)) * 2) * 512;
        int pos = ((g & 15) | (((k >> 3) & 3) << 4)) * 8 + (k & 7);
        rpk[fo + pos] = hi; rpk[fo + 512 + pos] = lo;
    } else if (idx < N1 + N2 + N3 + N4 + Gsz) {
        int g = idx - N1 - N2 - N3 - N4;
        bc[g] = kb[g] + rb[g];
        wt[g] = kW[g * (Dsz + 1) + Dsz] + rW[g * (Hsz + 1) + Hsz];
    }
}

__global__ __launch_bounds__(256) void pack_x(const float* __restrict__ x,
                                              u16* __restrict__ xpk) {
    int idx = blockIdx.x * 256 + threadIdx.x;
    int k = idx & 255, b = (idx >> 8) & 511, t = idx >> 17;
    float v = x[((size_t)b * Tsz + t) * Dsz + k];
    u16 hi = f2bf(v), lo = f2bf(v - bf2f(hi));
    size_t fo = (((size_t)t * 32 + (b >> 4)) * KTX + (k >> 5)) * 2 * 512;
    int pos = ((b & 15) | (((k >> 3) & 3) << 4)) * 8 + (k & 7);
    xpk[fo + pos] = hi;
    xpk[fo + 512 + pos] = lo;
}

__global__ __launch_bounds__(256) void pack_cw(const float* __restrict__ cW,
                                               u16* __restrict__ cpk) {
    int idx = blockIdx.x * 256 + threadIdx.x;
    if (idx >= Hsz * Hsz * CSs) return;
    int o = idx / (Hsz * CSs), k = idx % (Hsz * CSs);
    size_t fo = ((size_t)(o >> 4) * KTC + (k >> 5)) * 512;
    int pos = ((o & 15) | (((k >> 3) & 3) << 4)) * 8 + (k & 7);
    cpk[fo + pos] = f2bf(cW[idx]);
}

// ---- phase 1: serial recurrence. 32 blocks x 16 rows x 16 waves. ----
__global__ __launch_bounds__(1024, 1) void scan(const float* __restrict__ tme,
                                                char* __restrict__ ws,
                                                float* __restrict__ out) {
    const u16* wpk  = (const u16*)(ws + O_WPK);
    const u16* xwpk = (const u16*)(ws + O_XWPK);
    const float* bc = (const float*)(ws + O_BC);
    const float* wt = (const float*)(ws + O_WT);
    const u16* xpk  = (const u16*)(ws + O_XPK);

    int rg = blockIdx.x;
    u16* hbf = (u16*)(ws + O_HBF);

    float* out_seq  = out + (size_t)Bsz * Hsz;
    float* out_dist = out_seq + (size_t)Bsz * Tsz * Hsz;

    int tid = threadIdx.x;
    int wave = tid >> 6, lane = tid & 63, l15 = lane & 15, lk = lane >> 4;
    int b0 = rg * 16;

    __shared__ float s_xo[16][XOP];            // 101,120 B
    __shared__ u16   s_hpk[KTH][2][512];       // 24,576 B
    __shared__ u16   s_xa[2][16 * 512];        // 32,768 B   (x frags, dbuf)

    for (int i = tid; i < KTH * 2 * 256; i += 1024) ((unsigned*)s_hpk)[i] = 0u;
    // stage x(0) into buffer 0: wave w copies fragment w (kt = w>>1, hi/lo = w&1)
    {
        const u16* xs = xpk + ((size_t)(0 * 32 + rg) * KTX * 2) * 512;
        *(bf16x8*)&s_xa[0][wave * 512 + lane * 8] =
            *(const bf16x8*)(xs + (size_t)wave * 512 + lane * 8);
    }
    float cregs[6] = {0.f, 0.f, 0.f, 0.f, 0.f, 0.f};
    __syncthreads();

    for (int t = 0; t < Tsz; ++t) {
        // ---------- phase A: xo = x(t)@kW + h(t-1)@rW, all 98 g-tiles ----------
        {
            // stage x(t+1) into other buffer (read next iter, after >=1 sync)
            if (t + 1 < Tsz) {
                const u16* xs = xpk + ((size_t)((t + 1) * 32 + rg) * KTX * 2) * 512;
                *(bf16x8*)&s_xa[(t + 1) & 1][wave * 512 + lane * 8] =
                    *(const bf16x8*)(xs + (size_t)wave * 512 + lane * 8);
            }
            const u16* xcur = s_xa[t & 1];
            auto tile = [&](int gt) {
                f32x4 acc = {};
                #pragma unroll
                for (int kt = 0; kt < KTH; ++kt) {
                    bf16x8 ah = *(const bf16x8*)&s_hpk[kt][0][lane * 8];
                    bf16x8 al = *(const bf16x8*)&s_hpk[kt][1][lane * 8];
                    size_t fb = ((size_t)(gt * KTH + kt) * 2) * 512 + lane * 8;
                    bf16x8 bh = *(const bf16x8*)(wpk + fb);
                    bf16x8 bl = *(const bf16x8*)(wpk + fb + 512);
                    acc = MFMA(ah, bh, acc);
                    acc = MFMA(ah, bl, acc);
                    acc = MFMA(al, bh, acc);
                }
                #pragma unroll
                for (int kt = 0; kt < KTX; ++kt) {
                    bf16x8 xh = *(const bf16x8*)&xcur[(kt * 2) * 512 + lane * 8];
                    bf16x8 xl = *(const bf16x8*)&xcur[(kt * 2 + 1) * 512 + lane * 8];
                    size_t fb = ((size_t)(gt * KTX + kt) * 2) * 512 + lane * 8;
                    bf16x8 bh = *(const bf16x8*)(xwpk + fb);
                    bf16x8 bl = *(const bf16x8*)(xwpk + fb + 512);
                    acc = MFMA(xh, bh, acc);
                    acc = MFMA(xh, bl, acc);
                    acc = MFMA(xl, bh, acc);
                }
                int col = gt * 16 + l15;
                #pragma unroll
                for (int j = 0; j < 4; ++j)
                    s_xo[lk * 4 + j][col] = acc[j];
            };
            #pragma unroll
            for (int ti = 0; ti < 6; ++ti)
                tile(wave + (ti << 4));
            if (wave < 2) tile(96 + wave);
        }
        __syncthreads();

        // ---------- cell(t): row r = wave, 64 lanes x 6 channels ----------
        {
            int r = wave, c64 = lane;
            int b = b0 + r;
            float tv = tme[b * Tsz + t];
            float zf[6];
            #pragma unroll
            for (int g = 0; g < 6; ++g)
                zf[g] = s_xo[r][g] + bc[g] + tv * wt[g];   // LDS broadcast, all lanes
            float m = fmaxf(zf[0], fmaxf(zf[1], zf[2]));
            float e0 = expf(zf[0] - m), e1 = expf(zf[1] - m), e2 = expf(zf[2] - m);
            float inv = 1.f / (e0 + e1 + e2);
            float fm0 = e0 * inv, fm1 = fm0 + e1 * inv;
            float mw = fmaxf(zf[3], fmaxf(zf[4], zf[5]));
            float f0 = expf(zf[3] - mw), f1 = expf(zf[4] - mw), f2 = expf(zf[5] - mw);
            float invw = 1.f / (f0 + f1 + f2);
            float im2 = f2 * invw, im1 = f1 * invw + im2;
            if (c64 == 0)
                out_dist[(size_t)t * Bsz + b] = 1.f - (fm0 + fm1 + 1.f) * (1.f / 3.f);
            #pragma unroll
            for (int i = 0; i < 6; ++i) {
                int ch = i * 64 + c64;
                const int l = i >> 1;                 // static per unrolled i
                float fm = (l == 0) ? fm0 : ((l == 1) ? fm1 : 1.f);
                float im = (l == 0) ? 1.f : ((l == 1) ? im1 : im2);
                int g0 = 6 + ch, g1 = g0 + Hsz, g2 = g0 + 2 * Hsz, g3 = g0 + 3 * Hsz;
                float fg = sigm(s_xo[r][g0] + bc[g0] + tv * wt[g0]);
                float ig = sigm(s_xo[r][g1] + bc[g1] + tv * wt[g1]);
                float og = sigm(s_xo[r][g2] + bc[g2] + tv * wt[g2]);
                float ci = tanhf(s_xo[r][g3] + bc[g3] + tv * wt[g3]);
                float cl = cregs[i];
                float ov = fm * im;
                float cn = ov * (fg * cl + ig * ci) + (fm - ov) * cl + (im - ov) * ci;
                float hn = og * tanhf(cn);
                cregs[i] = cn;
                u16 hh = f2bf(hn);
                u16 hl = f2bf(hn - bf2f(hh));
                int pos = (r | (((ch >> 3) & 3) << 4)) * 8 + (ch & 7);
                s_hpk[ch >> 5][0][pos] = hh;
                s_hpk[ch >> 5][1][pos] = hl;
                size_t oi = ((size_t)b * Tsz + t) * Hsz + ch;
                out_seq[oi] = hn;          // h (f32) — post adds theme*conv
                hbf[oi] = hh;              // h (bf16) for conv A-build
            }
        }
        __syncthreads();
    }
}

// ---- phase 2: fully parallel over (b, t). Block = (b, 16 t's). ----
__global__ __launch_bounds__(512, 1) void post(const float* __restrict__ sb,
                                               const float* __restrict__ rsb,
                                               const float* __restrict__ cb,
                                               char* __restrict__ ws,
                                               float* __restrict__ out) {
    const u16* cpk = (const u16*)(ws + O_CPK);
    const u16* spk = (const u16*)(ws + O_SPK);
    const u16* rpk = (const u16*)(ws + O_RPK);
    const u16* hbf = (const u16*)(ws + O_HBF);

    float* out_last = out;
    float* out_seq  = out + (size_t)Bsz * Hsz;
    const float* out_dist = out_seq + (size_t)Bsz * Tsz * Hsz;

    int b = blockIdx.x, t0 = blockIdx.y * 16;
    int tid = threadIdx.x;
    int wave = tid >> 6, lane = tid & 63, l15 = lane & 15, lk = lane >> 4;

    __shared__ u16 s_apk[KTC][512];            // 122,880 B
    __shared__ u16 s_tpk[KTH * 2][512];        // 24,576 B
    __shared__ float th1s[16][68];
    __shared__ float s_ld[16][CSs];

    if (tid < 16) {
        int r = tid;
        float vals[CSs];
        float cum = 0.f;
        #pragma unroll
        for (int j = 0; j < CSs; ++j) {
            int tp = t0 + r - 9 + j;
            float d = (tp < 0) ? 0.f : out_dist[(size_t)tp * Bsz + b];
            cum += d;
            vals[j] = cum;
        }
        float mx = vals[0];
        #pragma unroll
        for (int j = 1; j < CSs; ++j) mx = fmaxf(mx, vals[j]);
        float sum = 0.f;
        #pragma unroll
        for (int j = 0; j < CSs; ++j) { vals[j] = expf(vals[j] - mx); sum += vals[j]; }
        float invs = 1.f / sum;
        #pragma unroll
        for (int j = 0; j < CSs; ++j) s_ld[r][j] = vals[j] * invs;
    }
    __syncthreads();

    // A-build: av[r][k=ch*10+j] = h(b,t0+r-9+j)[ch] * ld[r][j]; thm = mean_j
    for (int u = tid; u < 768; u += 512) {
        int r = u / 48, c8 = u % 48, ch0 = c8 * 8;
        float acc[8] = {0.f, 0.f, 0.f, 0.f, 0.f, 0.f, 0.f, 0.f};
        #pragma unroll
        for (int j = 0; j < CSs; ++j) {
            int tp = t0 + r - 9 + j;
            float ldv = s_ld[r][j];
            if (tp >= 0) {
                bf16x8 hv = *(const bf16x8*)(hbf + ((size_t)b * Tsz + tp) * Hsz + ch0);
                #pragma unroll
                for (int e = 0; e < 8; ++e) {
                    float av = bf2f((u16)hv[e]) * ldv;
                    int k = (ch0 + e) * CSs + j;
                    s_apk[k >> 5][(r | (((k >> 3) & 3) << 4)) * 8 + (k & 7)] = f2bf(av);
                    acc[e] += av;
                }
            } else {
                #pragma unroll
                for (int e = 0; e < 8; ++e) {
                    int k = (ch0 + e) * CSs + j;
                    s_apk[k >> 5][(r | (((k >> 3) & 3) << 4)) * 8 + (k & 7)] = 0;
                }
            }
        }
        int pos0 = (r | (((ch0 >> 3) & 3) << 4)) * 8;
        int kt2 = (ch0 >> 5) * 2;
        #pragma unroll
        for (int e = 0; e < 8; ++e) {
            float thm = acc[e] * 0.1f;
            u16 th = f2bf(thm), tl = f2bf(thm - bf2f(th));
            s_tpk[kt2][pos0 + e] = th;
            s_tpk[kt2 + 1][pos0 + e] = tl;
        }
    }
    __syncthreads();

    // conv MFMA (24 ot over 8 waves) + theme stage 1 (waves 0-3)
    f32x4 cacc[3] = {};
    for (int kt = 0; kt < KTC; ++kt) {
        bf16x8 a = *(const bf16x8*)&s_apk[kt][lane * 8];
        #pragma unroll
        for (int i = 0; i < 3; ++i) {
            int ot = wave * 3 + i;
            bf16x8 bv = *(const bf16x8*)(cpk + ((size_t)(ot * KTC + kt)) * 512 + lane * 8);
            cacc[i] = MFMA(a, bv, cacc[i]);
        }
    }
    if (wave < 4) {
        f32x4 a1 = {};
        for (int kt = 0; kt < KTH; ++kt) {
            bf16x8 ah = *(const bf16x8*)&s_tpk[kt * 2][lane * 8];
            bf16x8 al = *(const bf16x8*)&s_tpk[kt * 2 + 1][lane * 8];
            size_t bb = ((size_t)(wave * KTH + kt) * 2) * 512 + lane * 8;
            bf16x8 bh = *(const bf16x8*)(spk + bb);
            bf16x8 bl = *(const bf16x8*)(spk + bb + 512);
            a1 = MFMA(ah, bh, a1);
            a1 = MFMA(ah, bl, a1);
            a1 = MFMA(al, bh, a1);
        }
        int col = wave * 16 + l15;
        #pragma unroll
        for (int j = 0; j < 4; ++j)
            th1s[lk * 4 + j][col] = fmaxf(a1[j] + sb[col], 0.f);
    }
    __syncthreads();

    // theme stage 2 + epilogue: out = sigm(mlp)*(conv+cb) + h  (h already in out_seq)
    bf16x8 ah2[2], al2[2];
    #pragma unroll
    for (int kt = 0; kt < 2; ++kt) {
        bf16x8 zh, zl;
        #pragma unroll
        for (int e = 0; e < 8; ++e) {
            float v = th1s[l15][kt * 32 + lk * 8 + e];
            u16 hi = f2bf(v);
            zh[e] = (short)hi;
            zl[e] = (short)f2bf(v - bf2f(hi));
        }
        ah2[kt] = zh; al2[kt] = zl;
    }
    #pragma unroll
    for (int i = 0; i < 3; ++i) {
        int ot = wave * 3 + i;
        f32x4 a2 = {};
        #pragma unroll
        for (int kt = 0; kt < 2; ++kt) {
            size_t bb = ((size_t)(ot * 2 + kt) * 2) * 512 + lane * 8;
            bf16x8 bh = *(const bf16x8*)(rpk + bb);
            bf16x8 bl = *(const bf16x8*)(rpk + bb + 512);
            a2 = MFMA(ah2[kt], bh, a2);
            a2 = MFMA(ah2[kt], bl, a2);
            a2 = MFMA(al2[kt], bh, a2);
        }
        int col = ot * 16 + l15;
        #pragma unroll
        for (int j = 0; j < 4; ++j) {
            int row = lk * 4 + j;
            int tt = t0 + row;
            size_t oi = ((size_t)b * Tsz + tt) * Hsz + col;
            float convv = cacc[i][j] + cb[col];
            float th = sigm(a2[j] + rsb[col]);
            float val = th * convv + out_seq[oi];
            out_seq[oi] = val;
            if (tt == Tsz - 1) out_last[(size_t)b * Hsz + col] = val;
        }
    }
}

extern "C" void kernel_launch(void* const* d_in, const int* in_sizes, int n_in,
                              void* d_out, int out_size, void* d_ws, size_t ws_size,
                              hipStream_t stream) {
    const float* x   = (const float*)d_in[0];
    const float* tme = (const float*)d_in[1];
    const float* kW  = (const float*)d_in[2];
    const float* kb  = (const float*)d_in[3];
    const float* rW  = (const float*)d_in[4];
    const float* rb  = (const float*)d_in[5];
    const float* sW  = (const float*)d_in[6];
    const float* sb  = (const float*)d_in[7];
    const float* rsW = (const float*)d_in[8];
    const float* rsb = (const float*)d_in[9];
    const float* cW  = (const float*)d_in[10];
    const float* cb  = (const float*)d_in[11];

    char* wsb = (char*)d_ws;
    float* outp = (float*)d_out;

    u16* wpk  = (u16*)(wsb + O_WPK);
    u16* xwpk = (u16*)(wsb + O_XWPK);
    u16* cpk  = (u16*)(wsb + O_CPK);
    u16* spk  = (u16*)(wsb + O_SPK);
    u16* rpk  = (u16*)(wsb + O_RPK);
    float* bc = (float*)(wsb + O_BC);
    float* wt = (float*)(wsb + O_WT);
    u16* xpk  = (u16*)(wsb + O_XPK);

    {
        int nW = Gp * 384 + Gp * 256 + 64 * 384 + 384 * 64 + Gsz;
        build_w<<<(nW + 255) / 256, 256, 0, stream>>>(kW, kb, rW, rb, sW, rsW,
                                                      wpk, xwpk, spk, rpk, bc, wt);
    }
    pack_x<<<(Tsz * Bsz * Dsz) / 256, 256, 0, stream>>>(x, xpk);
    pack_cw<<<(Hsz * Hsz * CSs + 255) / 256, 256, 0, stream>>>(cW, cpk);

    scan<<<NRG, 1024, 0, stream>>>(tme, wsb, outp);
    post<<<dim3(Bsz, Tsz / 16), 512, 0, stream>>>(sb, rsb, cb, wsb, outp);
}